// Round 7
// baseline (7314.984 us; speedup 1.0000x reference)
//
#include <hip/hip_runtime.h>
#include <stdint.h>

// ---------------------------------------------------------------------------
// Binary net, single persistent kernel + tiny init node.
//   conv path  (blocks 0..255):   conv0+pack_w1 -> pack_h0 -> conv1 -> bn1 -> pack_a0
//   weight path(blocks 256..511): stream-pack fw0 (401MB) -> wp   [overlaps conv]
//   join: popcount GEMM (512 tiles, 1/block) -> fc0 epilogue -> fc1
// Co-residency: grid 512, launch_bounds(256,2) => VGPR<=256, LDS 32KB
//   => 2 blocks/CU on 256 CUs = 512 — exact fit, no deadlock.
// Weight path: 1 row/wave (1024 waves), 8-deep float4 ILP (fix of R6's
//   64-VGPR serialization: VGPR_Count=64, 87 GB/s, VALUBusy 4%).
// Bit order: word j=4Q+c holds elements k=256Q+4i+c at bit i (both operands).
// ---------------------------------------------------------------------------

static constexpr int BATCH = 256;
static constexpr int K0    = 100352;   // 128*784
static constexpr int KW    = 1568;     // K0/64
static constexpr int N1    = 1024;
static constexpr int KS    = 16;       // fc0 k-splits
static constexpr int JW    = 98;       // KW/KS
static constexpr int SUB   = 14;       // ap words per LDS subchunk
static constexpr int NS    = 7;        // JW/SUB
static constexpr unsigned ZCAP = 65536;
static constexpr int NBLK  = 512;
static constexpr int NC    = 256;      // conv-path blocks

__device__ __forceinline__ float fsign(float v){
    return (v > 0.f) ? 1.f : ((v < 0.f) ? -1.f : 0.f);
}

__device__ __forceinline__ void gbar(unsigned* c, unsigned goal)
{
    __threadfence();
    __syncthreads();
    if (threadIdx.x == 0) {
        unsigned prev = __hip_atomic_fetch_add(c, 1u, __ATOMIC_ACQ_REL,
                                               __HIP_MEMORY_SCOPE_AGENT);
        if (prev + 1u < goal) {
            while (__hip_atomic_load(c, __ATOMIC_ACQUIRE,
                                     __HIP_MEMORY_SCOPE_AGENT) < goal)
                __builtin_amdgcn_s_sleep(8);
        }
    }
    __syncthreads();
    __threadfence();
}

__global__ void k_init(unsigned* p)
{
    if (threadIdx.x < 16) p[threadIdx.x] = 0;   // 7 barrier ctrs + zcnt
}

__global__ __launch_bounds__(256, 2) void k_mega(
    const float* __restrict__ x,   const float* __restrict__ cw0,
    const float* __restrict__ cp0, const float* __restrict__ cg0,
    const float* __restrict__ cb0, const float* __restrict__ cw1,
    const float* __restrict__ cp1, const float* __restrict__ cg1,
    const float* __restrict__ cb1, const float* __restrict__ fw0,
    const float* __restrict__ fp0, const float* __restrict__ fg0,
    const float* __restrict__ fb0, const float* __restrict__ fw1,
    const float* __restrict__ fp1, const float* __restrict__ fg1,
    const float* __restrict__ fb1, const float* __restrict__ scale,
    unsigned* ctr, unsigned* zcnt, uint64_t* __restrict__ zlist,
    double* __restrict__ pS0, double* __restrict__ pQ0,
    double* __restrict__ pS1, double* __restrict__ pQ1,
    double* __restrict__ A1B1,
    int8_t* __restrict__ h0s, uint64_t* __restrict__ hp,
    int16_t* __restrict__ h1s, uint64_t* __restrict__ ap_t,
    uint64_t* __restrict__ wn1, uint64_t* __restrict__ wnz1,
    uint64_t* __restrict__ wp, int16_t* __restrict__ pcpart,
    float* __restrict__ af, float* __restrict__ out)
{
    __shared__ __align__(16) char smem[32768];
    const int bid  = blockIdx.x;
    const int tid  = threadIdx.x;
    const int wv   = tid >> 6;
    const int lane = tid & 63;

    if (bid < NC) {
        // ============================ conv path ============================
        {
            // ---- conv0 for image bid ----
            float (*img)[30]  = (float(*)[30])smem;
            float (*redS)[64] = (float(*)[64])(smem + 3616);
            float (*redQ)[64] = (float(*)[64])(smem + 3616 + 1024);
            const int b = bid;
            for (int i = tid; i < 900; i += 256) ((float*)img)[i] = 0.f;
            __syncthreads();
            for (int i = tid; i < 784; i += 256) {
                float v = x[b*784 + i];
                img[1 + i/28][1 + i%28] = fsign(v);
            }
            __syncthreads();
            float wsg[9];
            #pragma unroll
            for (int t = 0; t < 9; t++) wsg[t] = fsign(cw0[lane*9 + t]);
            float a = cp0[lane];
            float accS = 0.f, accQ = 0.f;
            for (int i = 0; i < 196; i++) {
                int p = wv*196 + i;
                int y = p / 28, xx = p % 28;
                float s = 0.f;
                #pragma unroll
                for (int dy = 0; dy < 3; dy++)
                    #pragma unroll
                    for (int dx = 0; dx < 3; dx++)
                        s += img[y+dy][xx+dx] * wsg[dy*3+dx];
                h0s[(size_t)(b*784 + p)*64 + lane] = (int8_t)(int)s;
                float v = (s >= 0.f) ? s : a*s;
                accS += v; accQ += v*v;
            }
            redS[wv][lane] = accS; redQ[wv][lane] = accQ;
            __syncthreads();
            if (tid < 64) {
                double s = (double)redS[0][tid] + redS[1][tid] + redS[2][tid] + redS[3][tid];
                double q = (double)redQ[0][tid] + redQ[1][tid] + redQ[2][tid] + redQ[3][tid];
                pS0[tid*256 + b] = s;
                pQ0[tid*256 + b] = q;
            }
            // ---- pack conv1 weights, grid-strided over conv waves ----
            for (int idx = bid*4 + wv; idx < 1152; idx += NC*4) {
                int oc = idx / 9, t = idx - oc*9;
                float w = cw1[oc*576 + lane*9 + t];
                uint64_t nm = __ballot(w < 0.f);
                uint64_t zm = __ballot(w != 0.f);
                if (lane == 0) { wn1[idx] = nm; wnz1[idx] = zm; }
            }
        }
        gbar(&ctr[0], NC);

        // ---- pack_h0: per-block LUT from pS0, then pack hp ----
        {
            unsigned* l = (unsigned*)smem;
            if (tid < 64) {
                double s0 = 0, s1 = 0, q0 = 0, q1 = 0;
                for (int b2 = 0; b2 < 256; b2 += 2) {
                    s0 += pS0[tid*256 + b2];   s1 += pS0[tid*256 + b2 + 1];
                    q0 += pQ0[tid*256 + b2];   q1 += pQ0[tid*256 + b2 + 1];
                }
                double S = s0 + s1, Q = q0 + q1;
                double mean = S * (1.0/200704.0);
                double var  = Q * (1.0/200704.0) - mean*mean;
                if (var < 0.0) var = 0.0;
                double A = (double)cg0[tid] / sqrt(var + 1e-5);
                double B = (double)cb0[tid] - mean*A;
                float a = cp0[tid];
                unsigned m = 0;
                for (int s = -9; s <= 9; ++s) {
                    float v = (s >= 0) ? (float)s : a*(float)s;
                    if (fma((double)v, A, B) < 0.0) m |= 1u << (s + 9);
                }
                l[tid] = m;
            }
            __syncthreads();
            for (int u = bid; u < 784; u += NC) {
                int pixel = u*256 + tid;
                const int4* p4 = (const int4*)(h0s + (size_t)pixel*64);
                int4 va = p4[0], vb = p4[1], vc = p4[2], vd = p4[3];
                int wa[16] = {va.x,va.y,va.z,va.w, vb.x,vb.y,vb.z,vb.w,
                              vc.x,vc.y,vc.z,vc.w, vd.x,vd.y,vd.z,vd.w};
                unsigned lo = 0, hi = 0;
                #pragma unroll
                for (int wi = 0; wi < 16; ++wi) {
                    unsigned w = (unsigned)wa[wi];
                    #pragma unroll
                    for (int c2 = 0; c2 < 4; ++c2) {
                        int ch = wi*4 + c2;
                        int s = (int)(signed char)(w >> (8*c2));
                        unsigned bit = (l[ch] >> (s + 9)) & 1u;
                        if (ch < 32) lo |= bit << ch; else hi |= bit << (ch - 32);
                    }
                }
                hp[pixel] = ((uint64_t)hi << 32) | lo;
            }
        }
        gbar(&ctr[1], NC);

        // ---- conv1 via XOR/popcount, race-free bn1 partials ----
        {
            float (*lS)[8] = (float(*)[8])smem;
            float (*lQ)[8] = (float(*)[8])(smem + 128);
            for (int u = bid; u < 16384; u += NC) {
                int ocg = u & 15, ptg = (u >> 4) & 3, b = u >> 6;
                int pt = ptg*4 + wv;
                bool active = (pt < 13);
                int p = active ? (pt*64 + lane) : 0;
                bool pvalid = active && (p < 784);
                int y = p / 28, xx = p % 28;
                uint64_t nb[9]; unsigned vmask = 0;
                #pragma unroll
                for (int dy = 0; dy < 3; dy++)
                    #pragma unroll
                    for (int dx = 0; dx < 3; dx++) {
                        int t = dy*3+dx;
                        int yy = y + dy - 1, xv = xx + dx - 1;
                        bool ok = (yy >= 0 && yy < 28 && xv < 28 && xv >= 0);
                        nb[t] = hp[b*784 + (ok ? (yy*28+xv) : 0)];
                        if (ok) vmask |= 1u << t;
                    }
                #pragma unroll
                for (int o = 0; o < 8; o++) {
                    int oc = ocg*8 + o;
                    int base = oc*9;
                    int acc = 0;
                    #pragma unroll
                    for (int t = 0; t < 9; t++) {
                        uint64_t wn = wn1[base+t], wz = wnz1[base+t];
                        if (vmask & (1u<<t))
                            acc += (int)__popcll(wz) - 2*(int)__popcll((nb[t] ^ wn) & wz);
                    }
                    if (pvalid) h1s[((size_t)b*128 + oc)*784 + p] = (int16_t)acc;
                    float pr = cp1[oc];
                    float v = pvalid ? ((acc >= 0) ? (float)acc : pr*(float)acc) : 0.f;
                    float s = v, q = v*v;
                    #pragma unroll
                    for (int off = 32; off; off >>= 1) {
                        s += __shfl_xor(s, off);
                        q += __shfl_xor(q, off);
                    }
                    if (lane == 0) { lS[wv][o] = s; lQ[wv][o] = q; }
                }
                __syncthreads();
                if (tid < 16) {
                    int o = tid & 7;
                    bool isQ = tid >= 8;
                    double v4 = isQ ? ((double)lQ[0][o] + lQ[1][o] + lQ[2][o] + lQ[3][o])
                                    : ((double)lS[0][o] + lS[1][o] + lS[2][o] + lS[3][o]);
                    double* dst = isQ ? pQ1 : pS1;
                    dst[(size_t)(ocg*8 + o)*1024 + (b*4 + ptg)] = v4;
                }
                __syncthreads();
            }
        }
        gbar(&ctr[2], NC);

        // ---- bn1 finalize ----
        if (bid < 128) {
            double* rs = (double*)smem;
            double* rq = rs + 256;
            int oc = bid;
            double s = 0.0, q = 0.0;
            #pragma unroll
            for (int i = 0; i < 4; ++i) {
                s += pS1[(size_t)oc*1024 + tid + 256*i];
                q += pQ1[(size_t)oc*1024 + tid + 256*i];
            }
            rs[tid] = s; rq[tid] = q;
            __syncthreads();
            for (int off = 128; off; off >>= 1) {
                if (tid < off) { rs[tid] += rs[tid+off]; rq[tid] += rq[tid+off]; }
                __syncthreads();
            }
            if (tid == 0) {
                double mean = rs[0] * (1.0/200704.0);
                double var  = rq[0] * (1.0/200704.0) - mean*mean;
                if (var < 0.0) var = 0.0;
                double A = (double)cg1[oc] / sqrt(var + 1e-5);
                A1B1[oc] = A; A1B1[128 + oc] = (double)cb1[oc] - mean*A;
            }
        }
        gbar(&ctr[3], NC);

        // ---- pack fc0 activations ----
        {
            int gw = bid*4 + wv;
            for (int u = gw; u < 100352; u += NC*4) {
                int b = u / 392, q = u - b*392;
                int k0 = q*256 + lane*4;
                short4 sv4 = *(const short4*)(h1s + (size_t)b*K0 + k0);
                int oc = k0 / 784;
                double A = A1B1[oc], B = A1B1[128 + oc];
                float aa = cp1[oc];
                int ss[4] = {sv4.x, sv4.y, sv4.z, sv4.w};
                uint64_t words[4];
                #pragma unroll
                for (int c = 0; c < 4; ++c) {
                    float s = (float)ss[c];
                    float v = (s >= 0.f) ? s : aa*s;
                    double t = fma((double)v, A, B);
                    words[c] = __ballot(t < 0.0);
                }
                if (lane == 0) {
                    #pragma unroll
                    for (int c = 0; c < 4; ++c)
                        ap_t[(size_t)(4*q + c)*256 + b] = words[c];
                }
            }
        }
    } else {
        // ============================ weight path ============================
        // 1 row per wave: 256 blocks x 4 waves = 1024 rows; 8-deep float4 ILP.
        int n = (bid - NC)*4 + wv;
        const float* src = fw0 + (size_t)n*K0 + lane*4;
        uint64_t* dst = wp + (size_t)n*KW;
        for (int go = 0; go < 49; ++go) {
            float4 f[8];
            #pragma unroll
            for (int u2 = 0; u2 < 8; ++u2)
                f[u2] = *(const float4*)(src + (size_t)(go*8 + u2)*256);
            #pragma unroll
            for (int u2 = 0; u2 < 8; ++u2) {
                int g = go*8 + u2;
                uint64_t g0 = __ballot(f[u2].x < 0.f);
                uint64_t g1 = __ballot(f[u2].y < 0.f);
                uint64_t g2 = __ballot(f[u2].z < 0.f);
                uint64_t g3 = __ballot(f[u2].w < 0.f);
                uint64_t z0 = __ballot(f[u2].x == 0.f);
                uint64_t z1 = __ballot(f[u2].y == 0.f);
                uint64_t z2 = __ballot(f[u2].z == 0.f);
                uint64_t z3 = __ballot(f[u2].w == 0.f);
                if (lane == 0) {
                    ulonglong2 a{g0, g1}, b2{g2, g3};
                    *(ulonglong2*)(dst + g*4)     = a;
                    *(ulonglong2*)(dst + g*4 + 2) = b2;
                    if (z0 | z1 | z2 | z3) {        // essentially never
                        uint64_t zz[4] = {z0, z1, z2, z3};
                        #pragma unroll
                        for (int c = 0; c < 4; ++c) if (zz[c]) {
                            unsigned id = atomicAdd(zcnt, 1u);
                            if (id < ZCAP) {
                                zlist[2*id]   = ((uint64_t)(unsigned)n << 32)
                                              | (unsigned)(4*g + c);
                                zlist[2*id+1] = zz[c];
                            }
                        }
                    }
                }
            }
        }
    }
    gbar(&ctr[4], NBLK);       // JOIN: ap_t, wp, wn/wnz, zlist all ready

    // ============================ fc0 GEMM: 1 tile/block ============================
    {
        uint64_t (*apL)[256] = (uint64_t(*)[256])smem;          // 28672 B
        uint64_t (*wTc)[14]  = (uint64_t(*)[14])(smem + 28672); //  3584 B
        int nt = bid & 31, ks = bid >> 5;     // 32 n-tiles x 16 k-splits
        int n0 = nt*32, j0 = ks*JW;
        int bq = tid & 31, nq = tid >> 5;
        int pc[8][4];
        #pragma unroll
        for (int i = 0; i < 8; i++)
            #pragma unroll
            for (int k = 0; k < 4; k++) pc[i][k] = 0;
        for (int c = 0; c < NS; ++c) {
            int jb = j0 + c*SUB;
            #pragma unroll
            for (int r = 0; r < SUB; ++r)
                apL[r][tid] = ap_t[(size_t)(jb + r)*256 + tid];
            if (tid < 224) {
                int row = tid / 7, wi = tid - row*7;
                ulonglong2 v = *(const ulonglong2*)(wp + (size_t)(n0+row)*KW + jb + wi*2);
                wTc[row][wi*2] = v.x; wTc[row][wi*2+1] = v.y;
            }
            __syncthreads();
            #pragma unroll
            for (int jj = 0; jj < SUB; ++jj) {
                uint64_t aw[8], ww[4];
                #pragma unroll
                for (int i = 0; i < 8; i++) aw[i] = apL[jj][bq + 32*i];
                #pragma unroll
                for (int k = 0; k < 4; k++) ww[k] = wTc[nq + 8*k][jj];
                #pragma unroll
                for (int i = 0; i < 8; i++)
                    #pragma unroll
                    for (int k = 0; k < 4; k++)
                        pc[i][k] += (int)__popcll(aw[i] ^ ww[k]);
            }
            __syncthreads();
        }
        #pragma unroll
        for (int k = 0; k < 4; k++) {
            int n = n0 + nq + 8*k;
            #pragma unroll
            for (int i = 0; i < 8; i++)
                pcpart[((size_t)ks*N1 + n)*BATCH + (bq + 32*i)] = (int16_t)pc[i][k];
        }
    }
    gbar(&ctr[5], NBLK);

    // ============================ fc0 epilogue ============================
    {
        double* rs  = (double*)smem;
        double* rq  = rs + 256;
        double* AB2 = rq + 256;
        for (int n = bid; n < N1; n += NBLK) {
            int b = tid;
            int pcs = 0;
            #pragma unroll
            for (int ks = 0; ks < KS; ks++)
                pcs += (int)pcpart[((size_t)ks*N1 + n)*BATCH + b];
            int s = K0 - 2*pcs;
            unsigned cnt = *zcnt; if (cnt > ZCAP) cnt = ZCAP;
            for (unsigned e = 0; e < cnt; ++e) {
                uint64_t key = zlist[2*e];
                if ((int)(key >> 32) == n) {
                    uint64_t zm = zlist[2*e+1];
                    uint64_t a = ap_t[(size_t)(key & 0xffffffffu)*256 + b];
                    s += 2*(int)__popcll(a & zm) - (int)__popcll(zm);
                }
            }
            float a = fp0[n];
            float v = (s >= 0) ? (float)s : a*(float)s;
            rs[b] = v; rq[b] = (double)v*(double)v;
            __syncthreads();
            for (int off = 128; off > 0; off >>= 1) {
                if (b < off) { rs[b] += rs[b+off]; rq[b] += rq[b+off]; }
                __syncthreads();
            }
            if (b == 0) {
                double mean = rs[0] / 256.0;
                double var  = rq[0] / 256.0 - mean*mean;
                if (var < 0.0) var = 0.0;
                double A = (double)fg0[n] / sqrt(var + 1e-5);
                AB2[0] = A; AB2[1] = (double)fb0[n] - mean*A;
            }
            __syncthreads();
            double t = fma((double)v, AB2[0], AB2[1]);
            af[(size_t)n*256 + b] = (t > 0.0) ? 1.f : ((t < 0.0) ? -1.f : 0.f);
            __syncthreads();
        }
    }
    gbar(&ctr[6], NBLK);

    // ============================ fc1 + bn + scale ============================
    if (bid < 10) {
        double* sv  = (double*)smem;
        double* ABj = sv + 256;
        int j = bid, b = tid;
        float acc = 0.f;
        for (int k = 0; k < 1024; ++k)
            acc += af[(size_t)k*256 + b] * fsign(fw1[j*1024 + k]);
        float a = fp1[j];
        float v = (acc >= 0.f) ? acc : a*acc;
        sv[b] = (double)v;
        __syncthreads();
        for (int off = 128; off > 0; off >>= 1) {
            if (b < off) sv[b] += sv[b+off];
            __syncthreads();
        }
        double mean = sv[0] / 256.0;
        __syncthreads();
        double d = (double)v - mean;
        sv[b] = d*d;
        __syncthreads();
        for (int off = 128; off > 0; off >>= 1) {
            if (b < off) sv[b] += sv[b+off];
            __syncthreads();
        }
        if (b == 0) {
            double var = sv[0] / 256.0;
            double A = (double)fg1[j] / sqrt(var + 1e-5);
            ABj[0] = A; ABj[1] = (double)fb1[j] - mean*A;
        }
        __syncthreads();
        out[b*10 + j] = (float)fma((double)v, ABj[0], ABj[1]) * scale[0];
    }
}

extern "C" void kernel_launch(void* const* d_in, const int* in_sizes, int n_in,
                              void* d_out, int out_size, void* d_ws, size_t ws_size,
                              hipStream_t stream)
{
    const float* x    = (const float*)d_in[0];
    const float* cw0  = (const float*)d_in[1];
    const float* cp0  = (const float*)d_in[2];
    const float* cg0  = (const float*)d_in[3];
    const float* cb0  = (const float*)d_in[4];
    const float* cw1  = (const float*)d_in[5];
    const float* cp1  = (const float*)d_in[6];
    const float* cg1  = (const float*)d_in[7];
    const float* cb1  = (const float*)d_in[8];
    const float* fw0  = (const float*)d_in[9];
    const float* fp0  = (const float*)d_in[10];
    const float* fg0  = (const float*)d_in[11];
    const float* fb0  = (const float*)d_in[12];
    const float* fw1  = (const float*)d_in[13];
    const float* fp1  = (const float*)d_in[14];
    const float* fg1  = (const float*)d_in[15];
    const float* fb1  = (const float*)d_in[16];
    const float* scale= (const float*)d_in[17];

    char* ws = (char*)d_ws;
    size_t off = 0;
    auto alloc = [&](size_t bytes)->char* {
        char* r = ws + off; off = (off + bytes + 255) & ~(size_t)255; return r; };

    unsigned* ctrz  = (unsigned*)alloc(256);        // ctr[0..7] + zcnt
    unsigned* ctr   = ctrz;
    unsigned* zcnt  = ctrz + 8;
    double*   pS0   = (double*)alloc((size_t)64*256*8);
    double*   pQ0   = (double*)alloc((size_t)64*256*8);
    double*   pS1   = (double*)alloc((size_t)128*1024*8);
    double*   pQ1   = (double*)alloc((size_t)128*1024*8);
    double*   A1B1  = (double*)alloc(256*8);
    int8_t*   h0s   = (int8_t*)alloc((size_t)256*784*64);
    uint64_t* hp    = (uint64_t*)alloc((size_t)256*784*8);
    int16_t*  h1s   = (int16_t*)alloc((size_t)256*128*784*2);
    uint64_t* ap_t  = (uint64_t*)alloc((size_t)KW*256*8);
    uint64_t* wn1   = (uint64_t*)alloc(1152*8);
    uint64_t* wnz1  = (uint64_t*)alloc(1152*8);
    uint64_t* wp    = (uint64_t*)alloc((size_t)N1*KW*8);
    int16_t*  pcpart= (int16_t*)alloc((size_t)KS*N1*BATCH*2);
    float*    af    = (float*)alloc((size_t)1024*256*4);
    uint64_t* zlist = (uint64_t*)alloc((size_t)ZCAP*16);
    (void)ws_size; (void)in_sizes; (void)n_in; (void)out_size;

    k_init<<<1, 64, 0, stream>>>(ctrz);
    k_mega<<<NBLK, 256, 0, stream>>>(
        x, cw0, cp0, cg0, cb0, cw1, cp1, cg1, cb1,
        fw0, fp0, fg0, fb0, fw1, fp1, fg1, fb1, scale,
        ctr, zcnt, zlist, pS0, pQ0, pS1, pQ1, A1B1,
        h0s, hp, h1s, ap_t, wn1, wnz1, wp, pcpart, af, (float*)d_out);
}

// Round 8
// 456.459 us; speedup vs baseline: 16.0255x; 16.0255x over previous
//
#include <hip/hip_runtime.h>
#include <stdint.h>

// ---------------------------------------------------------------------------
// Binary net (multi-kernel, R5 structure + conv1 restructure + merged fc1):
//   conv0(1->64) -> prelu -> bn -> bin      [conv0 + LUT-pack]
//   conv1(64->128) xor/popcount + fused bn1 partials (4 ptg per block)
//   fc0(100352->1024): fw0 pack fused into popcount GEMM (KS=49)
//   fc1(1024->10) single kernel (exact integer sums -> order-free)
// binarize(bn(x)) == sign(v*A_c + B_c), A/B in f64 from batch stats.
// Bit order: word j=4Q+c holds elements k=256Q+4i+c at bit i (both operands);
// popcount(x^y) invariant under common bit permutation.
// ---------------------------------------------------------------------------

static constexpr int BATCH = 256;
static constexpr int K0    = 100352;  // 128*784
static constexpr int KW    = 1568;    // K0/64
static constexpr int N1    = 1024;
static constexpr int KS2   = 49;      // fc0 k-splits
static constexpr int JW2   = 32;      // words per split
static constexpr int SUB2  = 8;       // ap words per LDS subchunk
static constexpr int NS2   = 4;       // JW2/SUB2
static constexpr unsigned ZCAP = 65536;

__device__ __forceinline__ float fsign(float v){
    return (v > 0.f) ? 1.f : ((v < 0.f) ? -1.f : 0.f);
}

// ---- pack conv1 weights (+popcounts) + zero stats/zcnt region (block 0) ----
__global__ __launch_bounds__(256) void k_pack_w1(const float* __restrict__ cw1,
        uint64_t* __restrict__ wn1, uint64_t* __restrict__ wnz1,
        int* __restrict__ wzc, int* __restrict__ zero_region)
{
    if (blockIdx.x == 0) {
        for (int i = threadIdx.x; i < 320; i += 256) zero_region[i] = 0;
    }
    int idx = blockIdx.x*4 + (threadIdx.x >> 6);     // (oc*9 + t)
    int lane = threadIdx.x & 63;                     // lane = in channel
    int oc = idx / 9, t = idx % 9;
    float w = cw1[oc*576 + lane*9 + t];
    uint64_t n = __ballot(w < 0.f);
    uint64_t z = __ballot(w != 0.f);
    if (lane == 0) { wn1[idx] = n; wnz1[idx] = z; wzc[idx] = (int)__popcll(z); }
}

// ---- conv block 0: sign(x) conv3x3 sign(cw0), prelu, bn0 stats (atomics) ----
__global__ __launch_bounds__(256) void k_conv0(const float* __restrict__ x,
        const float* __restrict__ cw0, const float* __restrict__ cp0,
        int8_t* __restrict__ h0s, double* __restrict__ S0, double* __restrict__ Q0)
{
    __shared__ float img[30][30];
    __shared__ float redS[4][64];
    __shared__ float redQ[4][64];
    int b = blockIdx.x;
    int tid = threadIdx.x;
    for (int i = tid; i < 900; i += 256) ((float*)img)[i] = 0.f;
    __syncthreads();
    for (int i = tid; i < 784; i += 256) {
        float v = x[b*784 + i];
        img[1 + i/28][1 + i%28] = fsign(v);
    }
    __syncthreads();
    int lane = tid & 63, wv = tid >> 6;   // lane = out channel
    float wsg[9];
    #pragma unroll
    for (int t = 0; t < 9; t++) wsg[t] = fsign(cw0[lane*9 + t]);
    float a = cp0[lane];
    float accS = 0.f, accQ = 0.f;
    for (int i = 0; i < 196; i++) {
        int p = wv*196 + i;
        int y = p / 28, xx = p % 28;
        float s = 0.f;
        #pragma unroll
        for (int dy = 0; dy < 3; dy++)
            #pragma unroll
            for (int dx = 0; dx < 3; dx++)
                s += img[y+dy][xx+dx] * wsg[dy*3+dx];
        h0s[(size_t)(b*784 + p)*64 + lane] = (int8_t)(int)s;  // exact small int
        float v = (s >= 0.f) ? s : a*s;
        accS += v; accQ += v*v;
    }
    redS[wv][lane] = accS; redQ[wv][lane] = accQ;
    __syncthreads();
    if (tid < 64) {
        double s = (double)redS[0][tid] + redS[1][tid] + redS[2][tid] + redS[3][tid];
        double q = (double)redQ[0][tid] + redQ[1][tid] + redQ[2][tid] + redQ[3][tid];
        atomicAdd(&S0[tid], s);
        atomicAdd(&Q0[tid], q);
    }
}

// ---- pack conv1 input (fused bn0 finalize -> 19-entry LUT per channel) ----
__global__ __launch_bounds__(256) void k_pack_h0(const int8_t* __restrict__ h0s,
        const double* __restrict__ S0, const double* __restrict__ Q0,
        const float* __restrict__ cg0, const float* __restrict__ cb0,
        const float* __restrict__ cp0, uint64_t* __restrict__ hp)
{
    __shared__ unsigned l[64];
    int tid = threadIdx.x;
    if (tid < 64) {
        double mean = S0[tid] * (1.0/200704.0);
        double var  = Q0[tid] * (1.0/200704.0) - mean*mean;
        if (var < 0.0) var = 0.0;
        double A = (double)cg0[tid] / sqrt(var + 1e-5);
        double B = (double)cb0[tid] - mean*A;
        float a = cp0[tid];
        unsigned m = 0;
        for (int s = -9; s <= 9; ++s) {          // conv0 sums in [-9,9]
            float v = (s >= 0) ? (float)s : a*(float)s;
            if (fma((double)v, A, B) < 0.0) m |= 1u << (s + 9);
        }
        l[tid] = m;
    }
    __syncthreads();
    int pixel = blockIdx.x*256 + tid;      // grid 784*256 == 200704 exact
    const int4* p4 = (const int4*)(h0s + (size_t)pixel*64);
    int4 va = p4[0], vb = p4[1], vc = p4[2], vd = p4[3];
    int wa[16] = {va.x,va.y,va.z,va.w, vb.x,vb.y,vb.z,vb.w,
                  vc.x,vc.y,vc.z,vc.w, vd.x,vd.y,vd.z,vd.w};
    unsigned lo = 0, hi = 0;
    #pragma unroll
    for (int wi = 0; wi < 16; ++wi) {
        unsigned w = (unsigned)wa[wi];
        #pragma unroll
        for (int c2 = 0; c2 < 4; ++c2) {
            int ch = wi*4 + c2;
            int s = (int)(signed char)(w >> (8*c2));
            unsigned bit = (l[ch] >> (s + 9)) & 1u;
            if (ch < 32) lo |= bit << ch; else hi |= bit << (ch - 32);
        }
    }
    hp[pixel] = ((uint64_t)hi << 32) | lo;
}

// ---- conv1 via XOR/popcount, 4 pixel-groups per block, fused bn1 partials ----
__global__ __launch_bounds__(256) void k_conv1(const uint64_t* __restrict__ hp,
        const uint64_t* __restrict__ wn1, const uint64_t* __restrict__ wnz1,
        const int* __restrict__ wzc, const float* __restrict__ cp1,
        int16_t* __restrict__ h1s, double* __restrict__ pS1, double* __restrict__ pQ1)
{
    __shared__ float lS[4][8];
    __shared__ float lQ[4][8];
    int bid = blockIdx.x;            // 4096 = 256 b x 16 ocg
    int ocg = bid & 15;
    int b   = bid >> 4;
    int wv = threadIdx.x >> 6, lane = threadIdx.x & 63;
    float pr[8];
    #pragma unroll
    for (int o = 0; o < 8; o++) pr[o] = cp1[ocg*8 + o];
    float sA[8], qA[8];
    #pragma unroll
    for (int o = 0; o < 8; o++) { sA[o] = 0.f; qA[o] = 0.f; }

    for (int ptg = 0; ptg < 4; ++ptg) {
        int pt = ptg*4 + wv;
        bool active = (pt < 13);
        int p = active ? (pt*64 + lane) : 0;
        bool pvalid = active && (p < 784);
        int y = p / 28, xx = p % 28;
        uint64_t nb[9]; unsigned vmask = 0;
        #pragma unroll
        for (int dy = 0; dy < 3; dy++)
            #pragma unroll
            for (int dx = 0; dx < 3; dx++) {
                int t = dy*3+dx;
                int yy = y + dy - 1, xv = xx + dx - 1;
                bool ok = (yy >= 0 && yy < 28 && xv >= 0 && xv < 28);
                nb[t] = hp[b*784 + (ok ? (yy*28+xv) : 0)];
                if (ok) vmask |= 1u << t;
            }
        #pragma unroll
        for (int o = 0; o < 8; o++) {
            int base = (ocg*8 + o)*9;
            int acc = 0;
            #pragma unroll
            for (int t = 0; t < 9; t++) {
                uint64_t wn = wn1[base+t], wz = wnz1[base+t];
                int wc = wzc[base+t];
                if (vmask & (1u<<t))
                    acc += wc - 2*(int)__popcll((nb[t] ^ wn) & wz);
            }
            if (pvalid) h1s[((size_t)b*128 + ocg*8 + o)*784 + p] = (int16_t)acc;
            float v = pvalid ? ((acc >= 0) ? (float)acc : pr[o]*(float)acc) : 0.f;
            sA[o] += v; qA[o] += v*v;
        }
    }
    #pragma unroll
    for (int o = 0; o < 8; o++) {
        float s = sA[o], q = qA[o];
        #pragma unroll
        for (int off = 32; off; off >>= 1) {
            s += __shfl_xor(s, off);
            q += __shfl_xor(q, off);
        }
        if (lane == 0) { lS[wv][o] = s; lQ[wv][o] = q; }
    }
    __syncthreads();
    if (threadIdx.x < 16) {
        int o = threadIdx.x & 7;
        bool isQ = threadIdx.x >= 8;
        double v4 = isQ ? ((double)lQ[0][o] + lQ[1][o] + lQ[2][o] + lQ[3][o])
                        : ((double)lS[0][o] + lS[1][o] + lS[2][o] + lS[3][o]);
        double* dst = isQ ? pQ1 : pS1;
        dst[(size_t)(ocg*8 + o)*256 + b] = v4;
    }
}

// ---- bn1 finalize: reduce [oc][256] partials -> (A,B) in f64 ----
__global__ __launch_bounds__(256) void k_bnfin1(const double* __restrict__ pS,
        const double* __restrict__ pQ, const float* __restrict__ g,
        const float* __restrict__ bb, double* __restrict__ AB)
{
    int oc = blockIdx.x;      // 128
    int tid = threadIdx.x;
    __shared__ double rs[256], rq[256];
    rs[tid] = pS[(size_t)oc*256 + tid];
    rq[tid] = pQ[(size_t)oc*256 + tid];
    __syncthreads();
    for (int off = 128; off; off >>= 1) {
        if (tid < off) { rs[tid] += rs[tid+off]; rq[tid] += rq[tid+off]; }
        __syncthreads();
    }
    if (tid == 0) {
        double mean = rs[0] * (1.0/200704.0);
        double var  = rq[0] * (1.0/200704.0) - mean*mean;
        if (var < 0.0) var = 0.0;
        double A = (double)g[oc] / sqrt(var + 1e-5);
        AB[oc] = A; AB[128 + oc] = (double)bb[oc] - mean*A;
    }
}

// ---- pack fc0 activations, interleaved order, ap_t[word j][batch b] ----
__global__ __launch_bounds__(256) void k_pack_a0(const int16_t* __restrict__ h1s,
        const float* __restrict__ cp1, const double* __restrict__ AB,
        uint64_t* __restrict__ ap_t)
{
    int blk = blockIdx.x;                 // 256*98 blocks
    int b  = blk / 98;
    int qg = blk % 98;
    int wv = threadIdx.x >> 6, lane = threadIdx.x & 63;
    int q  = qg*4 + wv;                   // 0..391
    int k0 = q*256 + lane*4;
    short4 sv = *(const short4*)(h1s + (size_t)b*K0 + k0);
    int oc = k0 / 784;                    // all 4 elements share oc (4 | 784)
    double A = AB[oc], B = AB[128 + oc];
    float a = cp1[oc];
    int ss[4] = {sv.x, sv.y, sv.z, sv.w};
    uint64_t words[4];
    #pragma unroll
    for (int c = 0; c < 4; ++c) {
        float s = (float)ss[c];
        float v = (s >= 0.f) ? s : a*s;
        double t = fma((double)v, A, B);
        words[c] = __ballot(t < 0.0);
    }
    if (lane == 0) {
        #pragma unroll
        for (int c = 0; c < 4; ++c)
            ap_t[(size_t)(4*q + c)*256 + b] = words[c];
    }
}

// ---- fused fc0: stream-pack this block's fw0 slice into LDS, then
//      XOR/popcount GEMM against packed activations ----
__global__ __launch_bounds__(256) void k_fc0g(const float* __restrict__ fw0,
        const uint64_t* __restrict__ ap_t, int16_t* __restrict__ pcpart,
        unsigned* __restrict__ zcnt, uint64_t* __restrict__ zlist)
{
    __shared__ uint64_t wT[32][33];       // +1 pad: kills bank conflicts
    __shared__ uint64_t apL[SUB2][256];
    int ks = blockIdx.x % KS2;            // consecutive blocks walk k (stream)
    int nt = blockIdx.x / KS2;
    int tid = threadIdx.x;
    int wv = tid >> 6, lane = tid & 63;
    int n0 = nt*32, j0 = ks*JW2;
    // ---- stage A: pack 32 rows x 2048 elements (256KB of fw0, read once) ----
    {
        const float* wsrc = fw0 + (size_t)(n0 + wv*8)*K0 + (size_t)(ks*8)*256 + lane*4;
        for (int r8 = 0; r8 < 8; ++r8) {
            const float* rowp = wsrc + (size_t)r8*K0;
            int row = wv*8 + r8;
            #pragma unroll
            for (int qq = 0; qq < 8; ++qq) {
                float4 w = *(const float4*)(rowp + qq*256);
                uint64_t g0 = __ballot(w.x < 0.f);
                uint64_t g1 = __ballot(w.y < 0.f);
                uint64_t g2 = __ballot(w.z < 0.f);
                uint64_t g3 = __ballot(w.w < 0.f);
                uint64_t z0 = __ballot(w.x == 0.f);
                uint64_t z1 = __ballot(w.y == 0.f);
                uint64_t z2 = __ballot(w.z == 0.f);
                uint64_t z3 = __ballot(w.w == 0.f);
                if (lane == 0) {
                    wT[row][qq*4+0] = g0;
                    wT[row][qq*4+1] = g1;
                    wT[row][qq*4+2] = g2;
                    wT[row][qq*4+3] = g3;
                    if (z0 | z1 | z2 | z3) {            // ~never
                        uint64_t zz[4] = {z0, z1, z2, z3};
                        #pragma unroll
                        for (int c = 0; c < 4; ++c) if (zz[c]) {
                            unsigned id = atomicAdd(zcnt, 1u);
                            if (id < ZCAP) {
                                unsigned j = (unsigned)((ks*8 + qq)*4 + c);
                                zlist[2*id]   = ((uint64_t)(unsigned)(n0+row) << 32) | j;
                                zlist[2*id+1] = zz[c];
                            }
                        }
                    }
                }
            }
        }
    }
    // ---- stage B: popcount GEMM ----
    int bq = tid & 31;            // b = bq + 32*i
    int nq = tid >> 5;            // n = n0 + nq + 8*k
    int pc[8][4];
    #pragma unroll
    for (int i = 0; i < 8; i++)
        #pragma unroll
        for (int k = 0; k < 4; k++) pc[i][k] = 0;
    for (int c = 0; c < NS2; c++) {
        #pragma unroll
        for (int r = 0; r < SUB2; r++)
            apL[r][tid] = ap_t[(size_t)(j0 + c*SUB2 + r)*256 + tid];
        __syncthreads();                  // covers wT on first pass
        #pragma unroll
        for (int jj = 0; jj < SUB2; jj++) {
            uint64_t aw[8], ww[4];
            #pragma unroll
            for (int i = 0; i < 8; i++) aw[i] = apL[jj][bq + 32*i];
            #pragma unroll
            for (int k = 0; k < 4; k++) ww[k] = wT[nq + 8*k][c*8 + jj];
            #pragma unroll
            for (int i = 0; i < 8; i++)
                #pragma unroll
                for (int k = 0; k < 4; k++)
                    pc[i][k] += (int)__popcll(aw[i] ^ ww[k]);
        }
        __syncthreads();
    }
    #pragma unroll
    for (int k = 0; k < 4; k++) {
        int n = n0 + nq + 8*k;
        #pragma unroll
        for (int i = 0; i < 8; i++)
            pcpart[((size_t)ks*N1 + n)*BATCH + (bq + 32*i)] = (int16_t)pc[i][k];
    }
}

// ---- fc0 epilogue: combine partials + zero-weight corrections, bn, binarize ----
__global__ __launch_bounds__(256) void k_fc0ep(const int16_t* __restrict__ pcpart,
        const unsigned* __restrict__ zcnt, const uint64_t* __restrict__ zlist,
        const uint64_t* __restrict__ ap_t, const float* __restrict__ fp0,
        const float* __restrict__ fg0, const float* __restrict__ fb0,
        float* __restrict__ af)
{
    int n = blockIdx.x, b = threadIdx.x;
    int pc = 0;
    #pragma unroll
    for (int ks = 0; ks < KS2; ks++) pc += (int)pcpart[((size_t)ks*N1 + n)*BATCH + b];
    int s = K0 - 2*pc;
    unsigned cnt = *zcnt; if (cnt > ZCAP) cnt = ZCAP;
    for (unsigned e = 0; e < cnt; ++e) {       // essentially never taken
        uint64_t key = zlist[2*e];
        if ((int)(key >> 32) == n) {
            uint64_t zm = zlist[2*e+1];
            uint64_t a = ap_t[(size_t)(key & 0xffffffffu)*256 + b];
            s += 2*(int)__popcll(a & zm) - (int)__popcll(zm);
        }
    }
    float a = fp0[n];
    float v = (s >= 0) ? (float)s : a*(float)s;
    __shared__ double rs[256], rq[256];
    rs[b] = v; rq[b] = (double)v*(double)v;
    __syncthreads();
    for (int off=128; off>0; off>>=1){
        if (b<off){ rs[b]+=rs[b+off]; rq[b]+=rq[b+off]; }
        __syncthreads();
    }
    __shared__ double AB[2];
    if (b == 0) {
        double mean = rs[0] / 256.0;
        double var = rq[0] / 256.0 - mean*mean;
        if (var < 0.0) var = 0.0;
        double A = (double)fg0[n] / sqrt(var + 1e-5);
        AB[0] = A; AB[1] = (double)fb0[n] - mean*A;
    }
    __syncthreads();
    double t = fma((double)v, AB[0], AB[1]);
    af[(size_t)n*256 + b] = (t > 0.0) ? 1.f : ((t < 0.0) ? -1.f : 0.f);
}

// ---- fc1: dot + prelu + bn(batch) + scale, one block per output j ----
// (af and sign(fw1) are exactly {-1,0,1}: sums are exact -> order-free)
__global__ __launch_bounds__(256) void k_fc1(const float* __restrict__ af,
        const float* __restrict__ fw1, const float* __restrict__ fp1,
        const float* __restrict__ fg1, const float* __restrict__ fb1,
        const float* __restrict__ scale, float* __restrict__ out)
{
    __shared__ double sv[256];
    __shared__ double ABj[2];
    int j = blockIdx.x, b = threadIdx.x;
    float acc = 0.f;
    for (int k = 0; k < 1024; ++k)
        acc += af[(size_t)k*256 + b] * fsign(fw1[j*1024 + k]);
    float a = fp1[j];
    float v = (acc >= 0.f) ? acc : a*acc;
    sv[b] = (double)v;
    __syncthreads();
    for (int off = 128; off > 0; off >>= 1) {
        if (b < off) sv[b] += sv[b+off];
        __syncthreads();
    }
    double mean = sv[0] / 256.0;
    __syncthreads();
    double d = (double)v - mean;
    sv[b] = d*d;
    __syncthreads();
    for (int off = 128; off > 0; off >>= 1) {
        if (b < off) sv[b] += sv[b+off];
        __syncthreads();
    }
    if (b == 0) {
        double var = sv[0] / 256.0;
        double A = (double)fg1[j] / sqrt(var + 1e-5);
        ABj[0] = A; ABj[1] = (double)fb1[j] - mean*A;
    }
    __syncthreads();
    out[b*10 + j] = (float)fma((double)v, ABj[0], ABj[1]) * scale[0];
}

extern "C" void kernel_launch(void* const* d_in, const int* in_sizes, int n_in,
                              void* d_out, int out_size, void* d_ws, size_t ws_size,
                              hipStream_t stream)
{
    const float* x    = (const float*)d_in[0];
    const float* cw0  = (const float*)d_in[1];
    const float* cp0  = (const float*)d_in[2];
    const float* cg0  = (const float*)d_in[3];
    const float* cb0  = (const float*)d_in[4];
    const float* cw1  = (const float*)d_in[5];
    const float* cp1  = (const float*)d_in[6];
    const float* cg1  = (const float*)d_in[7];
    const float* cb1  = (const float*)d_in[8];
    const float* fw0  = (const float*)d_in[9];
    const float* fp0  = (const float*)d_in[10];
    const float* fg0  = (const float*)d_in[11];
    const float* fb0  = (const float*)d_in[12];
    const float* fw1  = (const float*)d_in[13];
    const float* fp1  = (const float*)d_in[14];
    const float* fg1  = (const float*)d_in[15];
    const float* fb1  = (const float*)d_in[16];
    const float* scale= (const float*)d_in[17];

    char* ws = (char*)d_ws;
    size_t off = 0;
    auto alloc = [&](size_t bytes)->char* {
        char* r = ws + off; off = (off + bytes + 255) & ~(size_t)255; return r; };

    // zeroed-by-k_pack_w1-block0 region: bytes [0, 1280)
    double*   S0    = (double*)alloc(64*8);     // @0
    double*   Q0    = (double*)alloc(64*8);     // @512
    unsigned* zcnt  = (unsigned*)alloc(256);    // @1024
    // scratch (fully overwritten each call before use)
    double*   A1B1  = (double*)alloc(256*8);
    double*   pS1   = (double*)alloc((size_t)128*256*8);
    double*   pQ1   = (double*)alloc((size_t)128*256*8);
    int*      wzc   = (int*)alloc(1152*4);
    int8_t*   h0s   = (int8_t*)alloc((size_t)256*784*64);
    uint64_t* hp    = (uint64_t*)alloc((size_t)256*784*8);
    int16_t*  h1s   = (int16_t*)alloc((size_t)256*128*784*2);
    uint64_t* ap_t  = (uint64_t*)alloc((size_t)KW*256*8);
    uint64_t* wn1   = (uint64_t*)alloc(1152*8);
    uint64_t* wnz1  = (uint64_t*)alloc(1152*8);
    int16_t*  pcpart= (int16_t*)alloc((size_t)KS2*N1*BATCH*2);
    float*    af    = (float*)alloc((size_t)1024*256*4);
    uint64_t* zlist = (uint64_t*)alloc((size_t)ZCAP*16);
    (void)ws_size; (void)in_sizes; (void)n_in; (void)out_size;

    k_pack_w1<<<288,   256, 0, stream>>>(cw1, wn1, wnz1, wzc, (int*)d_ws);
    k_conv0  <<<256,   256, 0, stream>>>(x, cw0, cp0, h0s, S0, Q0);
    k_pack_h0<<<784,   256, 0, stream>>>(h0s, S0, Q0, cg0, cb0, cp0, hp);
    k_conv1  <<<4096,  256, 0, stream>>>(hp, wn1, wnz1, wzc, cp1, h1s, pS1, pQ1);
    k_bnfin1 <<<128,   256, 0, stream>>>(pS1, pQ1, cg1, cb1, A1B1);
    k_pack_a0<<<25088, 256, 0, stream>>>(h1s, cp1, A1B1, ap_t);
    k_fc0g   <<<KS2*32,256, 0, stream>>>(fw0, ap_t, pcpart, zcnt, zlist);
    k_fc0ep  <<<1024,  256, 0, stream>>>(pcpart, zcnt, zlist, ap_t, fp0, fg0, fb0, af);
    k_fc1    <<<10,    256, 0, stream>>>(af, fw1, fp1, fg1, fb1, scale, (float*)d_out);
}

// Round 9
// 382.890 us; speedup vs baseline: 19.1047x; 1.1921x over previous
//
#include <hip/hip_runtime.h>
#include <stdint.h>

// ---------------------------------------------------------------------------
// Binary net (R5 structure; only change vs R5: fc1a+fc1b merged into k_fc1).
//   conv0(1->64) -> prelu -> bn -> bin      [conv0 + LUT-pack]
//   conv1(64->128) xor/popcount + fused bn1 partials (R5 16384-block form)
//   fc0(100352->1024): fw0 pack fused into popcount GEMM (KS=49)
//   fc1(1024->10) single kernel (exact integer sums -> order-free)
// binarize(bn(x)) == sign(v*A_c + B_c), A/B in f64 from batch stats.
// Bit order: word j=4Q+c holds elements k=256Q+4i+c at bit i (both operands);
// popcount(x^y) invariant under common bit permutation.
// ---------------------------------------------------------------------------

static constexpr int BATCH = 256;
static constexpr int K0    = 100352;  // 128*784
static constexpr int KW    = 1568;    // K0/64
static constexpr int N1    = 1024;
static constexpr int KS2   = 49;      // fc0 k-splits
static constexpr int JW2   = 32;      // words per split
static constexpr int SUB2  = 8;       // ap words per LDS subchunk
static constexpr int NS2   = 4;       // JW2/SUB2
static constexpr unsigned ZCAP = 65536;

__device__ __forceinline__ float fsign(float v){
    return (v > 0.f) ? 1.f : ((v < 0.f) ? -1.f : 0.f);
}

// ---- pack conv1 weights + zero the stats/zcnt region (block 0) ----
__global__ __launch_bounds__(256) void k_pack_w1(const float* __restrict__ cw1,
        uint64_t* __restrict__ wn1, uint64_t* __restrict__ wnz1,
        int* __restrict__ zero_region)
{
    if (blockIdx.x == 0) {
        for (int i = threadIdx.x; i < 320; i += 256) zero_region[i] = 0;
    }
    int idx = blockIdx.x*4 + (threadIdx.x >> 6);     // (oc*9 + t)
    int lane = threadIdx.x & 63;                     // lane = in channel
    int oc = idx / 9, t = idx % 9;
    float w = cw1[oc*576 + lane*9 + t];
    uint64_t n = __ballot(w < 0.f);
    uint64_t z = __ballot(w != 0.f);
    if (lane == 0) { wn1[idx] = n; wnz1[idx] = z; }
}

// ---- conv block 0: sign(x) conv3x3 sign(cw0), prelu, bn0 stats (atomics) ----
__global__ __launch_bounds__(256) void k_conv0(const float* __restrict__ x,
        const float* __restrict__ cw0, const float* __restrict__ cp0,
        int8_t* __restrict__ h0s, double* __restrict__ S0, double* __restrict__ Q0)
{
    __shared__ float img[30][30];
    __shared__ float redS[4][64];
    __shared__ float redQ[4][64];
    int b = blockIdx.x;
    int tid = threadIdx.x;
    for (int i = tid; i < 900; i += 256) ((float*)img)[i] = 0.f;
    __syncthreads();
    for (int i = tid; i < 784; i += 256) {
        float v = x[b*784 + i];
        img[1 + i/28][1 + i%28] = fsign(v);
    }
    __syncthreads();
    int lane = tid & 63, wv = tid >> 6;   // lane = out channel
    float wsg[9];
    #pragma unroll
    for (int t = 0; t < 9; t++) wsg[t] = fsign(cw0[lane*9 + t]);
    float a = cp0[lane];
    float accS = 0.f, accQ = 0.f;
    for (int i = 0; i < 196; i++) {
        int p = wv*196 + i;
        int y = p / 28, xx = p % 28;
        float s = 0.f;
        #pragma unroll
        for (int dy = 0; dy < 3; dy++)
            #pragma unroll
            for (int dx = 0; dx < 3; dx++)
                s += img[y+dy][xx+dx] * wsg[dy*3+dx];
        h0s[(size_t)(b*784 + p)*64 + lane] = (int8_t)(int)s;  // exact small int
        float v = (s >= 0.f) ? s : a*s;
        accS += v; accQ += v*v;
    }
    redS[wv][lane] = accS; redQ[wv][lane] = accQ;
    __syncthreads();
    if (tid < 64) {
        double s = (double)redS[0][tid] + redS[1][tid] + redS[2][tid] + redS[3][tid];
        double q = (double)redQ[0][tid] + redQ[1][tid] + redQ[2][tid] + redQ[3][tid];
        atomicAdd(&S0[tid], s);
        atomicAdd(&Q0[tid], q);
    }
}

// ---- pack conv1 input (fused bn0 finalize -> 19-entry LUT per channel) ----
__global__ __launch_bounds__(256) void k_pack_h0(const int8_t* __restrict__ h0s,
        const double* __restrict__ S0, const double* __restrict__ Q0,
        const float* __restrict__ cg0, const float* __restrict__ cb0,
        const float* __restrict__ cp0, uint64_t* __restrict__ hp)
{
    __shared__ unsigned l[64];
    int tid = threadIdx.x;
    if (tid < 64) {
        double mean = S0[tid] * (1.0/200704.0);
        double var  = Q0[tid] * (1.0/200704.0) - mean*mean;
        if (var < 0.0) var = 0.0;
        double A = (double)cg0[tid] / sqrt(var + 1e-5);
        double B = (double)cb0[tid] - mean*A;
        float a = cp0[tid];
        unsigned m = 0;
        for (int s = -9; s <= 9; ++s) {          // conv0 sums in [-9,9]
            float v = (s >= 0) ? (float)s : a*(float)s;
            if (fma((double)v, A, B) < 0.0) m |= 1u << (s + 9);
        }
        l[tid] = m;
    }
    __syncthreads();
    int pixel = blockIdx.x*256 + tid;      // grid 784*256 == 200704 exact
    const int4* p4 = (const int4*)(h0s + (size_t)pixel*64);
    int4 va = p4[0], vb = p4[1], vc = p4[2], vd = p4[3];
    int wa[16] = {va.x,va.y,va.z,va.w, vb.x,vb.y,vb.z,vb.w,
                  vc.x,vc.y,vc.z,vc.w, vd.x,vd.y,vd.z,vd.w};
    unsigned lo = 0, hi = 0;
    #pragma unroll
    for (int wi = 0; wi < 16; ++wi) {
        unsigned w = (unsigned)wa[wi];
        #pragma unroll
        for (int c2 = 0; c2 < 4; ++c2) {
            int ch = wi*4 + c2;
            int s = (int)(signed char)(w >> (8*c2));
            unsigned bit = (l[ch] >> (s + 9)) & 1u;
            if (ch < 32) lo |= bit << ch; else hi |= bit << (ch - 32);
        }
    }
    hp[pixel] = ((uint64_t)hi << 32) | lo;
}

// ---- conv1 via XOR/popcount + fused bn1 partials (R5 form, 16384 blocks) ----
__global__ __launch_bounds__(256) void k_conv1(const uint64_t* __restrict__ hp,
        const uint64_t* __restrict__ wn1, const uint64_t* __restrict__ wnz1,
        const float* __restrict__ cp1, int16_t* __restrict__ h1s,
        double* __restrict__ pS1, double* __restrict__ pQ1)
{
    __shared__ float lS[4][8];
    __shared__ float lQ[4][8];
    int bid = blockIdx.x;
    int ocg = bid & 15;
    int ptg = (bid >> 4) & 3;
    int b   = bid >> 6;
    int wv = threadIdx.x >> 6, lane = threadIdx.x & 63;
    int pt = ptg*4 + wv;
    bool active = (pt < 13);
    int p = active ? (pt*64 + lane) : 0;
    bool pvalid = active && (p < 784);
    int y = p / 28, xx = p % 28;
    uint64_t nb[9]; unsigned vmask = 0;
    #pragma unroll
    for (int dy = 0; dy < 3; dy++)
        #pragma unroll
        for (int dx = 0; dx < 3; dx++) {
            int t = dy*3+dx;
            int yy = y + dy - 1, xv = xx + dx - 1;
            bool ok = (yy >= 0 && yy < 28 && xv >= 0 && xv < 28);
            nb[t] = hp[b*784 + (ok ? (yy*28+xv) : 0)];
            if (ok) vmask |= 1u << t;
        }
    #pragma unroll
    for (int o = 0; o < 8; o++) {
        int oc = ocg*8 + o;
        int base = oc*9;
        int acc = 0;
        #pragma unroll
        for (int t = 0; t < 9; t++) {
            uint64_t wn = wn1[base+t], wz = wnz1[base+t];
            if (vmask & (1u<<t))
                acc += (int)__popcll(wz) - 2*(int)__popcll((nb[t] ^ wn) & wz);
        }
        if (pvalid) h1s[((size_t)b*128 + oc)*784 + p] = (int16_t)acc;
        float pr = cp1[oc];
        float v = pvalid ? ((acc >= 0) ? (float)acc : pr*(float)acc) : 0.f;
        float s = v, q = v*v;
        #pragma unroll
        for (int off = 32; off; off >>= 1) {
            s += __shfl_xor(s, off);
            q += __shfl_xor(q, off);
        }
        if (lane == 0) { lS[wv][o] = s; lQ[wv][o] = q; }
    }
    __syncthreads();
    if (threadIdx.x < 16) {
        int o = threadIdx.x & 7;
        bool isQ = threadIdx.x >= 8;
        double v4 = isQ ? ((double)lQ[0][o] + lQ[1][o] + lQ[2][o] + lQ[3][o])
                        : ((double)lS[0][o] + lS[1][o] + lS[2][o] + lS[3][o]);
        double* dst = isQ ? pQ1 : pS1;
        dst[(size_t)(ocg*8 + o)*1024 + (b*4 + ptg)] = v4;
    }
}

// ---- bn1 finalize: reduce [oc][1024] partials -> (A,B) in f64 ----
__global__ __launch_bounds__(256) void k_bnfin1(const double* __restrict__ pS,
        const double* __restrict__ pQ, const float* __restrict__ g,
        const float* __restrict__ bb, double* __restrict__ AB)
{
    int oc = blockIdx.x;      // 128
    int tid = threadIdx.x;
    double s = 0.0, q = 0.0;
    #pragma unroll
    for (int i = 0; i < 4; ++i) {
        s += pS[(size_t)oc*1024 + tid + 256*i];
        q += pQ[(size_t)oc*1024 + tid + 256*i];
    }
    __shared__ double rs[256], rq[256];
    rs[tid] = s; rq[tid] = q;
    __syncthreads();
    for (int off = 128; off; off >>= 1) {
        if (tid < off) { rs[tid] += rs[tid+off]; rq[tid] += rq[tid+off]; }
        __syncthreads();
    }
    if (tid == 0) {
        double mean = rs[0] * (1.0/200704.0);
        double var  = rq[0] * (1.0/200704.0) - mean*mean;
        if (var < 0.0) var = 0.0;
        double A = (double)g[oc] / sqrt(var + 1e-5);
        AB[oc] = A; AB[128 + oc] = (double)bb[oc] - mean*A;
    }
}

// ---- pack fc0 activations, interleaved order, ap_t[word j][batch b] ----
__global__ __launch_bounds__(256) void k_pack_a0(const int16_t* __restrict__ h1s,
        const float* __restrict__ cp1, const double* __restrict__ AB,
        uint64_t* __restrict__ ap_t)
{
    int blk = blockIdx.x;                 // 256*98 blocks
    int b  = blk / 98;
    int qg = blk % 98;
    int wv = threadIdx.x >> 6, lane = threadIdx.x & 63;
    int q  = qg*4 + wv;                   // 0..391
    int k0 = q*256 + lane*4;
    short4 sv = *(const short4*)(h1s + (size_t)b*K0 + k0);
    int oc = k0 / 784;                    // all 4 elements share oc (4 | 784)
    double A = AB[oc], B = AB[128 + oc];
    float a = cp1[oc];
    int ss[4] = {sv.x, sv.y, sv.z, sv.w};
    uint64_t words[4];
    #pragma unroll
    for (int c = 0; c < 4; ++c) {
        float s = (float)ss[c];
        float v = (s >= 0.f) ? s : a*s;
        double t = fma((double)v, A, B);
        words[c] = __ballot(t < 0.0);
    }
    if (lane == 0) {
        #pragma unroll
        for (int c = 0; c < 4; ++c)
            ap_t[(size_t)(4*q + c)*256 + b] = words[c];
    }
}

// ---- fused fc0: stream-pack this block's fw0 slice into LDS, then
//      XOR/popcount GEMM against packed activations ----
__global__ __launch_bounds__(256) void k_fc0g(const float* __restrict__ fw0,
        const uint64_t* __restrict__ ap_t, int16_t* __restrict__ pcpart,
        unsigned* __restrict__ zcnt, uint64_t* __restrict__ zlist)
{
    __shared__ uint64_t wT[32][33];       // +1 pad: kills bank conflicts
    __shared__ uint64_t apL[SUB2][256];
    int ks = blockIdx.x % KS2;            // consecutive blocks walk k (stream)
    int nt = blockIdx.x / KS2;
    int tid = threadIdx.x;
    int wv = tid >> 6, lane = tid & 63;
    int n0 = nt*32, j0 = ks*JW2;
    // ---- stage A: pack 32 rows x 2048 elements (256KB of fw0, read once) ----
    {
        const float* wsrc = fw0 + (size_t)(n0 + wv*8)*K0 + (size_t)(ks*8)*256 + lane*4;
        for (int r8 = 0; r8 < 8; ++r8) {
            const float* rowp = wsrc + (size_t)r8*K0;
            int row = wv*8 + r8;
            #pragma unroll
            for (int qq = 0; qq < 8; ++qq) {
                float4 w = *(const float4*)(rowp + qq*256);
                uint64_t g0 = __ballot(w.x < 0.f);
                uint64_t g1 = __ballot(w.y < 0.f);
                uint64_t g2 = __ballot(w.z < 0.f);
                uint64_t g3 = __ballot(w.w < 0.f);
                uint64_t z0 = __ballot(w.x == 0.f);
                uint64_t z1 = __ballot(w.y == 0.f);
                uint64_t z2 = __ballot(w.z == 0.f);
                uint64_t z3 = __ballot(w.w == 0.f);
                if (lane == 0) {
                    wT[row][qq*4+0] = g0;
                    wT[row][qq*4+1] = g1;
                    wT[row][qq*4+2] = g2;
                    wT[row][qq*4+3] = g3;
                    if (z0 | z1 | z2 | z3) {            // ~never
                        uint64_t zz[4] = {z0, z1, z2, z3};
                        #pragma unroll
                        for (int c = 0; c < 4; ++c) if (zz[c]) {
                            unsigned id = atomicAdd(zcnt, 1u);
                            if (id < ZCAP) {
                                unsigned j = (unsigned)((ks*8 + qq)*4 + c);
                                zlist[2*id]   = ((uint64_t)(unsigned)(n0+row) << 32) | j;
                                zlist[2*id+1] = zz[c];
                            }
                        }
                    }
                }
            }
        }
    }
    // ---- stage B: popcount GEMM ----
    int bq = tid & 31;            // b = bq + 32*i
    int nq = tid >> 5;            // n = n0 + nq + 8*k
    int pc[8][4];
    #pragma unroll
    for (int i = 0; i < 8; i++)
        #pragma unroll
        for (int k = 0; k < 4; k++) pc[i][k] = 0;
    for (int c = 0; c < NS2; c++) {
        #pragma unroll
        for (int r = 0; r < SUB2; r++)
            apL[r][tid] = ap_t[(size_t)(j0 + c*SUB2 + r)*256 + tid];
        __syncthreads();                  // covers wT on first pass
        #pragma unroll
        for (int jj = 0; jj < SUB2; jj++) {
            uint64_t aw[8], ww[4];
            #pragma unroll
            for (int i = 0; i < 8; i++) aw[i] = apL[jj][bq + 32*i];
            #pragma unroll
            for (int k = 0; k < 4; k++) ww[k] = wT[nq + 8*k][c*8 + jj];
            #pragma unroll
            for (int i = 0; i < 8; i++)
                #pragma unroll
                for (int k = 0; k < 4; k++)
                    pc[i][k] += (int)__popcll(aw[i] ^ ww[k]);
        }
        __syncthreads();
    }
    #pragma unroll
    for (int k = 0; k < 4; k++) {
        int n = n0 + nq + 8*k;
        #pragma unroll
        for (int i = 0; i < 8; i++)
            pcpart[((size_t)ks*N1 + n)*BATCH + (bq + 32*i)] = (int16_t)pc[i][k];
    }
}

// ---- fc0 epilogue: combine partials + zero-weight corrections, bn, binarize ----
__global__ __launch_bounds__(256) void k_fc0ep(const int16_t* __restrict__ pcpart,
        const unsigned* __restrict__ zcnt, const uint64_t* __restrict__ zlist,
        const uint64_t* __restrict__ ap_t, const float* __restrict__ fp0,
        const float* __restrict__ fg0, const float* __restrict__ fb0,
        float* __restrict__ af)
{
    int n = blockIdx.x, b = threadIdx.x;
    int pc = 0;
    #pragma unroll
    for (int ks = 0; ks < KS2; ks++) pc += (int)pcpart[((size_t)ks*N1 + n)*BATCH + b];
    int s = K0 - 2*pc;
    unsigned cnt = *zcnt; if (cnt > ZCAP) cnt = ZCAP;
    for (unsigned e = 0; e < cnt; ++e) {       // essentially never taken
        uint64_t key = zlist[2*e];
        if ((int)(key >> 32) == n) {
            uint64_t zm = zlist[2*e+1];
            uint64_t a = ap_t[(size_t)(key & 0xffffffffu)*256 + b];
            s += 2*(int)__popcll(a & zm) - (int)__popcll(zm);
        }
    }
    float a = fp0[n];
    float v = (s >= 0) ? (float)s : a*(float)s;
    __shared__ double rs[256], rq[256];
    rs[b] = v; rq[b] = (double)v*(double)v;
    __syncthreads();
    for (int off=128; off>0; off>>=1){
        if (b<off){ rs[b]+=rs[b+off]; rq[b]+=rq[b+off]; }
        __syncthreads();
    }
    __shared__ double AB[2];
    if (b == 0) {
        double mean = rs[0] / 256.0;
        double var = rq[0] / 256.0 - mean*mean;
        if (var < 0.0) var = 0.0;
        double A = (double)fg0[n] / sqrt(var + 1e-5);
        AB[0] = A; AB[1] = (double)fb0[n] - mean*A;
    }
    __syncthreads();
    double t = fma((double)v, AB[0], AB[1]);
    af[(size_t)n*256 + b] = (t > 0.0) ? 1.f : ((t < 0.0) ? -1.f : 0.f);
}

// ---- fc1: dot + prelu + bn(batch) + scale, one block per output j ----
// (af and sign(fw1) are exactly {-1,0,1}: sums are exact -> order-free)
__global__ __launch_bounds__(256) void k_fc1(const float* __restrict__ af,
        const float* __restrict__ fw1, const float* __restrict__ fp1,
        const float* __restrict__ fg1, const float* __restrict__ fb1,
        const float* __restrict__ scale, float* __restrict__ out)
{
    __shared__ double sv[256];
    __shared__ double ABj[2];
    int j = blockIdx.x, b = threadIdx.x;
    float acc = 0.f;
    for (int k = 0; k < 1024; ++k)
        acc += af[(size_t)k*256 + b] * fsign(fw1[j*1024 + k]);
    float a = fp1[j];
    float v = (acc >= 0.f) ? acc : a*acc;
    sv[b] = (double)v;
    __syncthreads();
    for (int off = 128; off > 0; off >>= 1) {
        if (b < off) sv[b] += sv[b+off];
        __syncthreads();
    }
    double mean = sv[0] / 256.0;
    __syncthreads();
    double d = (double)v - mean;
    sv[b] = d*d;
    __syncthreads();
    for (int off = 128; off > 0; off >>= 1) {
        if (b < off) sv[b] += sv[b+off];
        __syncthreads();
    }
    if (b == 0) {
        double var = sv[0] / 256.0;
        double A = (double)fg1[j] / sqrt(var + 1e-5);
        ABj[0] = A; ABj[1] = (double)fb1[j] - mean*A;
    }
    __syncthreads();
    out[b*10 + j] = (float)fma((double)v, ABj[0], ABj[1]) * scale[0];
}

extern "C" void kernel_launch(void* const* d_in, const int* in_sizes, int n_in,
                              void* d_out, int out_size, void* d_ws, size_t ws_size,
                              hipStream_t stream)
{
    const float* x    = (const float*)d_in[0];
    const float* cw0  = (const float*)d_in[1];
    const float* cp0  = (const float*)d_in[2];
    const float* cg0  = (const float*)d_in[3];
    const float* cb0  = (const float*)d_in[4];
    const float* cw1  = (const float*)d_in[5];
    const float* cp1  = (const float*)d_in[6];
    const float* cg1  = (const float*)d_in[7];
    const float* cb1  = (const float*)d_in[8];
    const float* fw0  = (const float*)d_in[9];
    const float* fp0  = (const float*)d_in[10];
    const float* fg0  = (const float*)d_in[11];
    const float* fb0  = (const float*)d_in[12];
    const float* fw1  = (const float*)d_in[13];
    const float* fp1  = (const float*)d_in[14];
    const float* fg1  = (const float*)d_in[15];
    const float* fb1  = (const float*)d_in[16];
    const float* scale= (const float*)d_in[17];

    char* ws = (char*)d_ws;
    size_t off = 0;
    auto alloc = [&](size_t bytes)->char* {
        char* r = ws + off; off = (off + bytes + 255) & ~(size_t)255; return r; };

    // zeroed-by-k_pack_w1-block0 region: bytes [0, 1280)
    double*   S0    = (double*)alloc(64*8);     // @0
    double*   Q0    = (double*)alloc(64*8);     // @512
    unsigned* zcnt  = (unsigned*)alloc(256);    // @1024
    // scratch (fully overwritten each call before use)
    double*   A1B1  = (double*)alloc(256*8);
    double*   pS1   = (double*)alloc((size_t)128*1024*8);
    double*   pQ1   = (double*)alloc((size_t)128*1024*8);
    int8_t*   h0s   = (int8_t*)alloc((size_t)256*784*64);
    uint64_t* hp    = (uint64_t*)alloc((size_t)256*784*8);
    int16_t*  h1s   = (int16_t*)alloc((size_t)256*128*784*2);
    uint64_t* ap_t  = (uint64_t*)alloc((size_t)KW*256*8);
    uint64_t* wn1   = (uint64_t*)alloc(1152*8);
    uint64_t* wnz1  = (uint64_t*)alloc(1152*8);
    int16_t*  pcpart= (int16_t*)alloc((size_t)KS2*N1*BATCH*2);
    float*    af    = (float*)alloc((size_t)1024*256*4);
    uint64_t* zlist = (uint64_t*)alloc((size_t)ZCAP*16);
    (void)ws_size; (void)in_sizes; (void)n_in; (void)out_size;

    k_pack_w1<<<288,   256, 0, stream>>>(cw1, wn1, wnz1, (int*)d_ws);
    k_conv0  <<<256,   256, 0, stream>>>(x, cw0, cp0, h0s, S0, Q0);
    k_pack_h0<<<784,   256, 0, stream>>>(h0s, S0, Q0, cg0, cb0, cp0, hp);
    k_conv1  <<<16384, 256, 0, stream>>>(hp, wn1, wnz1, cp1, h1s, pS1, pQ1);
    k_bnfin1 <<<128,   256, 0, stream>>>(pS1, pQ1, cg1, cb1, A1B1);
    k_pack_a0<<<25088, 256, 0, stream>>>(h1s, cp1, A1B1, ap_t);
    k_fc0g   <<<KS2*32,256, 0, stream>>>(fw0, ap_t, pcpart, zcnt, zlist);
    k_fc0ep  <<<1024,  256, 0, stream>>>(pcpart, zcnt, zlist, ap_t, fp0, fg0, fb0, af);
    k_fc1    <<<10,    256, 0, stream>>>(af, fw1, fp1, fg1, fb1, scale, (float*)d_out);
}

// Round 10
// 368.212 us; speedup vs baseline: 19.8662x; 1.0399x over previous
//
#include <hip/hip_runtime.h>
#include <stdint.h>

// ---------------------------------------------------------------------------
// Binary net (R5 structure; changes vs R5:
//   - conv0 writes bn0 partials pS0[c][b] (no atomics, no pre-zeroing)
//   - pack_w1 folded into conv0 tail (grid-stride), block 0 zeroes zcnt
//   - pack_h0 reduces the 256 partials when building its LUT
//   => 10 nodes -> 9; fc1a/fc1b restored to the R5 two-kernel form.)
// binarize(bn(x)) == sign(v*A_c + B_c), A/B in f64 from batch stats.
// Bit order: word j=4Q+c holds elements k=256Q+4i+c at bit i (both operands);
// popcount(x^y) invariant under common bit permutation.
// ---------------------------------------------------------------------------

static constexpr int BATCH = 256;
static constexpr int K0    = 100352;  // 128*784
static constexpr int KW    = 1568;    // K0/64
static constexpr int N1    = 1024;
static constexpr int KS2   = 49;      // fc0 k-splits
static constexpr int JW2   = 32;      // words per split
static constexpr int SUB2  = 8;       // ap words per LDS subchunk
static constexpr int NS2   = 4;       // JW2/SUB2
static constexpr unsigned ZCAP = 65536;

__device__ __forceinline__ float fsign(float v){
    return (v > 0.f) ? 1.f : ((v < 0.f) ? -1.f : 0.f);
}

// ---- conv0 (sign(x) conv3x3 sign(cw0), prelu, bn0 partials) + pack_w1 tail ----
__global__ __launch_bounds__(256) void k_conv0(const float* __restrict__ x,
        const float* __restrict__ cw0, const float* __restrict__ cp0,
        const float* __restrict__ cw1,
        int8_t* __restrict__ h0s, double* __restrict__ pS0, double* __restrict__ pQ0,
        uint64_t* __restrict__ wn1, uint64_t* __restrict__ wnz1,
        unsigned* __restrict__ zcnt)
{
    __shared__ float img[30][30];
    __shared__ float redS[4][64];
    __shared__ float redQ[4][64];
    int b = blockIdx.x;
    int tid = threadIdx.x;
    if (b == 0 && tid == 0) *zcnt = 0u;     // consumed by k_fc0g (later node)
    for (int i = tid; i < 900; i += 256) ((float*)img)[i] = 0.f;
    __syncthreads();
    for (int i = tid; i < 784; i += 256) {
        float v = x[b*784 + i];
        img[1 + i/28][1 + i%28] = fsign(v);
    }
    __syncthreads();
    int lane = tid & 63, wv = tid >> 6;   // lane = out channel
    float wsg[9];
    #pragma unroll
    for (int t = 0; t < 9; t++) wsg[t] = fsign(cw0[lane*9 + t]);
    float a = cp0[lane];
    float accS = 0.f, accQ = 0.f;
    for (int i = 0; i < 196; i++) {
        int p = wv*196 + i;
        int y = p / 28, xx = p % 28;
        float s = 0.f;
        #pragma unroll
        for (int dy = 0; dy < 3; dy++)
            #pragma unroll
            for (int dx = 0; dx < 3; dx++)
                s += img[y+dy][xx+dx] * wsg[dy*3+dx];
        h0s[(size_t)(b*784 + p)*64 + lane] = (int8_t)(int)s;  // exact small int
        float v = (s >= 0.f) ? s : a*s;
        accS += v; accQ += v*v;
    }
    redS[wv][lane] = accS; redQ[wv][lane] = accQ;
    __syncthreads();
    if (tid < 64) {
        double s = (double)redS[0][tid] + redS[1][tid] + redS[2][tid] + redS[3][tid];
        double q = (double)redQ[0][tid] + redQ[1][tid] + redQ[2][tid] + redQ[3][tid];
        pS0[tid*256 + b] = s;               // race-free partials [c][b]
        pQ0[tid*256 + b] = q;
    }
    // ---- pack conv1 weights, grid-strided over 1024 wave-units ----
    for (int idx = b*4 + wv; idx < 1152; idx += 1024) {
        int oc = idx / 9, t = idx - oc*9;
        float w = cw1[oc*576 + lane*9 + t];
        uint64_t nm = __ballot(w < 0.f);
        uint64_t zm = __ballot(w != 0.f);
        if (lane == 0) { wn1[idx] = nm; wnz1[idx] = zm; }
    }
}

// ---- pack conv1 input (bn0 finalize from partials -> 19-entry LUT) ----
__global__ __launch_bounds__(256) void k_pack_h0(const int8_t* __restrict__ h0s,
        const double* __restrict__ pS0, const double* __restrict__ pQ0,
        const float* __restrict__ cg0, const float* __restrict__ cb0,
        const float* __restrict__ cp0, uint64_t* __restrict__ hp)
{
    __shared__ unsigned l[64];
    int tid = threadIdx.x;
    if (tid < 64) {
        double s0 = 0, s1 = 0, q0 = 0, q1 = 0;
        for (int b2 = 0; b2 < 256; b2 += 2) {
            s0 += pS0[tid*256 + b2];   s1 += pS0[tid*256 + b2 + 1];
            q0 += pQ0[tid*256 + b2];   q1 += pQ0[tid*256 + b2 + 1];
        }
        double S = s0 + s1, Q = q0 + q1;
        double mean = S * (1.0/200704.0);
        double var  = Q * (1.0/200704.0) - mean*mean;
        if (var < 0.0) var = 0.0;
        double A = (double)cg0[tid] / sqrt(var + 1e-5);
        double B = (double)cb0[tid] - mean*A;
        float a = cp0[tid];
        unsigned m = 0;
        for (int s = -9; s <= 9; ++s) {          // conv0 sums in [-9,9]
            float v = (s >= 0) ? (float)s : a*(float)s;
            if (fma((double)v, A, B) < 0.0) m |= 1u << (s + 9);
        }
        l[tid] = m;
    }
    __syncthreads();
    int pixel = blockIdx.x*256 + tid;      // grid 784*256 == 200704 exact
    const int4* p4 = (const int4*)(h0s + (size_t)pixel*64);
    int4 va = p4[0], vb = p4[1], vc = p4[2], vd = p4[3];
    int wa[16] = {va.x,va.y,va.z,va.w, vb.x,vb.y,vb.z,vb.w,
                  vc.x,vc.y,vc.z,vc.w, vd.x,vd.y,vd.z,vd.w};
    unsigned lo = 0, hi = 0;
    #pragma unroll
    for (int wi = 0; wi < 16; ++wi) {
        unsigned w = (unsigned)wa[wi];
        #pragma unroll
        for (int c2 = 0; c2 < 4; ++c2) {
            int ch = wi*4 + c2;
            int s = (int)(signed char)(w >> (8*c2));
            unsigned bit = (l[ch] >> (s + 9)) & 1u;
            if (ch < 32) lo |= bit << ch; else hi |= bit << (ch - 32);
        }
    }
    hp[pixel] = ((uint64_t)hi << 32) | lo;
}

// ---- conv1 via XOR/popcount + fused bn1 partials (R5 form, 16384 blocks) ----
__global__ __launch_bounds__(256) void k_conv1(const uint64_t* __restrict__ hp,
        const uint64_t* __restrict__ wn1, const uint64_t* __restrict__ wnz1,
        const float* __restrict__ cp1, int16_t* __restrict__ h1s,
        double* __restrict__ pS1, double* __restrict__ pQ1)
{
    __shared__ float lS[4][8];
    __shared__ float lQ[4][8];
    int bid = blockIdx.x;
    int ocg = bid & 15;
    int ptg = (bid >> 4) & 3;
    int b   = bid >> 6;
    int wv = threadIdx.x >> 6, lane = threadIdx.x & 63;
    int pt = ptg*4 + wv;
    bool active = (pt < 13);
    int p = active ? (pt*64 + lane) : 0;
    bool pvalid = active && (p < 784);
    int y = p / 28, xx = p % 28;
    uint64_t nb[9]; unsigned vmask = 0;
    #pragma unroll
    for (int dy = 0; dy < 3; dy++)
        #pragma unroll
        for (int dx = 0; dx < 3; dx++) {
            int t = dy*3+dx;
            int yy = y + dy - 1, xv = xx + dx - 1;
            bool ok = (yy >= 0 && yy < 28 && xv >= 0 && xv < 28);
            nb[t] = hp[b*784 + (ok ? (yy*28+xv) : 0)];
            if (ok) vmask |= 1u << t;
        }
    #pragma unroll
    for (int o = 0; o < 8; o++) {
        int oc = ocg*8 + o;
        int base = oc*9;
        int acc = 0;
        #pragma unroll
        for (int t = 0; t < 9; t++) {
            uint64_t wn = wn1[base+t], wz = wnz1[base+t];
            if (vmask & (1u<<t))
                acc += (int)__popcll(wz) - 2*(int)__popcll((nb[t] ^ wn) & wz);
        }
        if (pvalid) h1s[((size_t)b*128 + oc)*784 + p] = (int16_t)acc;
        float pr = cp1[oc];
        float v = pvalid ? ((acc >= 0) ? (float)acc : pr*(float)acc) : 0.f;
        float s = v, q = v*v;
        #pragma unroll
        for (int off = 32; off; off >>= 1) {
            s += __shfl_xor(s, off);
            q += __shfl_xor(q, off);
        }
        if (lane == 0) { lS[wv][o] = s; lQ[wv][o] = q; }
    }
    __syncthreads();
    if (threadIdx.x < 16) {
        int o = threadIdx.x & 7;
        bool isQ = threadIdx.x >= 8;
        double v4 = isQ ? ((double)lQ[0][o] + lQ[1][o] + lQ[2][o] + lQ[3][o])
                        : ((double)lS[0][o] + lS[1][o] + lS[2][o] + lS[3][o]);
        double* dst = isQ ? pQ1 : pS1;
        dst[(size_t)(ocg*8 + o)*1024 + (b*4 + ptg)] = v4;
    }
}

// ---- bn1 finalize: reduce [oc][1024] partials -> (A,B) in f64 ----
__global__ __launch_bounds__(256) void k_bnfin1(const double* __restrict__ pS,
        const double* __restrict__ pQ, const float* __restrict__ g,
        const float* __restrict__ bb, double* __restrict__ AB)
{
    int oc = blockIdx.x;      // 128
    int tid = threadIdx.x;
    double s = 0.0, q = 0.0;
    #pragma unroll
    for (int i = 0; i < 4; ++i) {
        s += pS[(size_t)oc*1024 + tid + 256*i];
        q += pQ[(size_t)oc*1024 + tid + 256*i];
    }
    __shared__ double rs[256], rq[256];
    rs[tid] = s; rq[tid] = q;
    __syncthreads();
    for (int off = 128; off; off >>= 1) {
        if (tid < off) { rs[tid] += rs[tid+off]; rq[tid] += rq[tid+off]; }
        __syncthreads();
    }
    if (tid == 0) {
        double mean = rs[0] * (1.0/200704.0);
        double var  = rq[0] * (1.0/200704.0) - mean*mean;
        if (var < 0.0) var = 0.0;
        double A = (double)g[oc] / sqrt(var + 1e-5);
        AB[oc] = A; AB[128 + oc] = (double)bb[oc] - mean*A;
    }
}

// ---- pack fc0 activations, interleaved order, ap_t[word j][batch b] ----
__global__ __launch_bounds__(256) void k_pack_a0(const int16_t* __restrict__ h1s,
        const float* __restrict__ cp1, const double* __restrict__ AB,
        uint64_t* __restrict__ ap_t)
{
    int blk = blockIdx.x;                 // 256*98 blocks
    int b  = blk / 98;
    int qg = blk % 98;
    int wv = threadIdx.x >> 6, lane = threadIdx.x & 63;
    int q  = qg*4 + wv;                   // 0..391
    int k0 = q*256 + lane*4;
    short4 sv = *(const short4*)(h1s + (size_t)b*K0 + k0);
    int oc = k0 / 784;                    // all 4 elements share oc (4 | 784)
    double A = AB[oc], B = AB[128 + oc];
    float a = cp1[oc];
    int ss[4] = {sv.x, sv.y, sv.z, sv.w};
    uint64_t words[4];
    #pragma unroll
    for (int c = 0; c < 4; ++c) {
        float s = (float)ss[c];
        float v = (s >= 0.f) ? s : a*s;
        double t = fma((double)v, A, B);
        words[c] = __ballot(t < 0.0);
    }
    if (lane == 0) {
        #pragma unroll
        for (int c = 0; c < 4; ++c)
            ap_t[(size_t)(4*q + c)*256 + b] = words[c];
    }
}

// ---- fused fc0: stream-pack this block's fw0 slice into LDS, then
//      XOR/popcount GEMM against packed activations ----
__global__ __launch_bounds__(256) void k_fc0g(const float* __restrict__ fw0,
        const uint64_t* __restrict__ ap_t, int16_t* __restrict__ pcpart,
        unsigned* __restrict__ zcnt, uint64_t* __restrict__ zlist)
{
    __shared__ uint64_t wT[32][33];       // +1 pad: kills bank conflicts
    __shared__ uint64_t apL[SUB2][256];
    int ks = blockIdx.x % KS2;            // consecutive blocks walk k (stream)
    int nt = blockIdx.x / KS2;
    int tid = threadIdx.x;
    int wv = tid >> 6, lane = tid & 63;
    int n0 = nt*32, j0 = ks*JW2;
    // ---- stage A: pack 32 rows x 2048 elements (256KB of fw0, read once) ----
    {
        const float* wsrc = fw0 + (size_t)(n0 + wv*8)*K0 + (size_t)(ks*8)*256 + lane*4;
        for (int r8 = 0; r8 < 8; ++r8) {
            const float* rowp = wsrc + (size_t)r8*K0;
            int row = wv*8 + r8;
            #pragma unroll
            for (int qq = 0; qq < 8; ++qq) {
                float4 w = *(const float4*)(rowp + qq*256);
                uint64_t g0 = __ballot(w.x < 0.f);
                uint64_t g1 = __ballot(w.y < 0.f);
                uint64_t g2 = __ballot(w.z < 0.f);
                uint64_t g3 = __ballot(w.w < 0.f);
                uint64_t z0 = __ballot(w.x == 0.f);
                uint64_t z1 = __ballot(w.y == 0.f);
                uint64_t z2 = __ballot(w.z == 0.f);
                uint64_t z3 = __ballot(w.w == 0.f);
                if (lane == 0) {
                    wT[row][qq*4+0] = g0;
                    wT[row][qq*4+1] = g1;
                    wT[row][qq*4+2] = g2;
                    wT[row][qq*4+3] = g3;
                    if (z0 | z1 | z2 | z3) {            // ~never
                        uint64_t zz[4] = {z0, z1, z2, z3};
                        #pragma unroll
                        for (int c = 0; c < 4; ++c) if (zz[c]) {
                            unsigned id = atomicAdd(zcnt, 1u);
                            if (id < ZCAP) {
                                unsigned j = (unsigned)((ks*8 + qq)*4 + c);
                                zlist[2*id]   = ((uint64_t)(unsigned)(n0+row) << 32) | j;
                                zlist[2*id+1] = zz[c];
                            }
                        }
                    }
                }
            }
        }
    }
    // ---- stage B: popcount GEMM ----
    int bq = tid & 31;            // b = bq + 32*i
    int nq = tid >> 5;            // n = n0 + nq + 8*k
    int pc[8][4];
    #pragma unroll
    for (int i = 0; i < 8; i++)
        #pragma unroll
        for (int k = 0; k < 4; k++) pc[i][k] = 0;
    for (int c = 0; c < NS2; c++) {
        #pragma unroll
        for (int r = 0; r < SUB2; r++)
            apL[r][tid] = ap_t[(size_t)(j0 + c*SUB2 + r)*256 + tid];
        __syncthreads();                  // covers wT on first pass
        #pragma unroll
        for (int jj = 0; jj < SUB2; jj++) {
            uint64_t aw[8], ww[4];
            #pragma unroll
            for (int i = 0; i < 8; i++) aw[i] = apL[jj][bq + 32*i];
            #pragma unroll
            for (int k = 0; k < 4; k++) ww[k] = wT[nq + 8*k][c*8 + jj];
            #pragma unroll
            for (int i = 0; i < 8; i++)
                #pragma unroll
                for (int k = 0; k < 4; k++)
                    pc[i][k] += (int)__popcll(aw[i] ^ ww[k]);
        }
        __syncthreads();
    }
    #pragma unroll
    for (int k = 0; k < 4; k++) {
        int n = n0 + nq + 8*k;
        #pragma unroll
        for (int i = 0; i < 8; i++)
            pcpart[((size_t)ks*N1 + n)*BATCH + (bq + 32*i)] = (int16_t)pc[i][k];
    }
}

// ---- fc0 epilogue: combine partials + zero-weight corrections, bn, binarize ----
__global__ __launch_bounds__(256) void k_fc0ep(const int16_t* __restrict__ pcpart,
        const unsigned* __restrict__ zcnt, const uint64_t* __restrict__ zlist,
        const uint64_t* __restrict__ ap_t, const float* __restrict__ fp0,
        const float* __restrict__ fg0, const float* __restrict__ fb0,
        float* __restrict__ af)
{
    int n = blockIdx.x, b = threadIdx.x;
    int pc = 0;
    #pragma unroll
    for (int ks = 0; ks < KS2; ks++) pc += (int)pcpart[((size_t)ks*N1 + n)*BATCH + b];
    int s = K0 - 2*pc;
    unsigned cnt = *zcnt; if (cnt > ZCAP) cnt = ZCAP;
    for (unsigned e = 0; e < cnt; ++e) {       // essentially never taken
        uint64_t key = zlist[2*e];
        if ((int)(key >> 32) == n) {
            uint64_t zm = zlist[2*e+1];
            uint64_t a = ap_t[(size_t)(key & 0xffffffffu)*256 + b];
            s += 2*(int)__popcll(a & zm) - (int)__popcll(zm);
        }
    }
    float a = fp0[n];
    float v = (s >= 0) ? (float)s : a*(float)s;
    __shared__ double rs[256], rq[256];
    rs[b] = v; rq[b] = (double)v*(double)v;
    __syncthreads();
    for (int off=128; off>0; off>>=1){
        if (b<off){ rs[b]+=rs[b+off]; rq[b]+=rq[b+off]; }
        __syncthreads();
    }
    __shared__ double AB[2];
    if (b == 0) {
        double mean = rs[0] / 256.0;
        double var = rq[0] / 256.0 - mean*mean;
        if (var < 0.0) var = 0.0;
        double A = (double)fg0[n] / sqrt(var + 1e-5);
        AB[0] = A; AB[1] = (double)fb0[n] - mean*A;
    }
    __syncthreads();
    double t = fma((double)v, AB[0], AB[1]);
    af[(size_t)n*256 + b] = (t > 0.0) ? 1.f : ((t < 0.0) ? -1.f : 0.f);
}

// ---- fc1 partial dots (k-split) ----
__global__ __launch_bounds__(256) void k_fc1a(const float* __restrict__ af,
        const float* __restrict__ fw1, float* __restrict__ part9)
{
    __shared__ float swL[10][32];
    int ks = blockIdx.x, b = threadIdx.x;
    for (int i = b; i < 320; i += 256) {
        int j = i / 32, kk = i % 32;
        swL[j][kk] = fsign(fw1[j*1024 + ks*32 + kk]);
    }
    __syncthreads();
    float acc[10];
    #pragma unroll
    for (int j=0;j<10;j++) acc[j]=0.f;
    for (int kk = 0; kk < 32; kk++) {
        float a = af[(size_t)(ks*32+kk)*256 + b];
        #pragma unroll
        for (int j=0;j<10;j++) acc[j] += a * swL[j][kk];
    }
    #pragma unroll
    for (int j=0;j<10;j++) part9[((size_t)ks*256 + b)*10 + j] = acc[j];
}

// ---- fc1 finish: prelu, bn over batch, scale ----
__global__ __launch_bounds__(256) void k_fc1b(const float* __restrict__ part9,
        const float* __restrict__ fp1, const float* __restrict__ fg1,
        const float* __restrict__ fb1, const float* __restrict__ scale,
        float* __restrict__ out)
{
    int b = threadIdx.x;
    float v[10];
    #pragma unroll
    for (int j=0;j<10;j++) v[j]=0.f;
    for (int ks=0; ks<32; ks++)
        #pragma unroll
        for (int j=0;j<10;j++) v[j] += part9[((size_t)ks*256+b)*10 + j];
    #pragma unroll
    for (int j=0;j<10;j++){
        float a = fp1[j];
        v[j] = (v[j] >= 0.f) ? v[j] : a*v[j];
    }
    __shared__ double sv[256];
    __shared__ double AB[2][10];
    for (int j=0;j<10;j++){
        sv[b] = (double)v[j];
        __syncthreads();
        for (int off=128;off>0;off>>=1){ if(b<off) sv[b]+=sv[b+off]; __syncthreads(); }
        double mean = sv[0]/256.0;
        __syncthreads();
        double d = (double)v[j]-mean;
        sv[b] = d*d;
        __syncthreads();
        for (int off=128;off>0;off>>=1){ if(b<off) sv[b]+=sv[b+off]; __syncthreads(); }
        if (b==0){
            double var = sv[0]/256.0;
            double A = (double)fg1[j]/sqrt(var+1e-5);
            AB[0][j]=A; AB[1][j]=(double)fb1[j] - mean*A;
        }
        __syncthreads();
    }
    float sc = scale[0];
    #pragma unroll
    for (int j=0;j<10;j++)
        out[b*10+j] = (float)fma((double)v[j], AB[0][j], AB[1][j]) * sc;
}

extern "C" void kernel_launch(void* const* d_in, const int* in_sizes, int n_in,
                              void* d_out, int out_size, void* d_ws, size_t ws_size,
                              hipStream_t stream)
{
    const float* x    = (const float*)d_in[0];
    const float* cw0  = (const float*)d_in[1];
    const float* cp0  = (const float*)d_in[2];
    const float* cg0  = (const float*)d_in[3];
    const float* cb0  = (const float*)d_in[4];
    const float* cw1  = (const float*)d_in[5];
    const float* cp1  = (const float*)d_in[6];
    const float* cg1  = (const float*)d_in[7];
    const float* cb1  = (const float*)d_in[8];
    const float* fw0  = (const float*)d_in[9];
    const float* fp0  = (const float*)d_in[10];
    const float* fg0  = (const float*)d_in[11];
    const float* fb0  = (const float*)d_in[12];
    const float* fw1  = (const float*)d_in[13];
    const float* fp1  = (const float*)d_in[14];
    const float* fg1  = (const float*)d_in[15];
    const float* fb1  = (const float*)d_in[16];
    const float* scale= (const float*)d_in[17];

    char* ws = (char*)d_ws;
    size_t off = 0;
    auto alloc = [&](size_t bytes)->char* {
        char* r = ws + off; off = (off + bytes + 255) & ~(size_t)255; return r; };

    unsigned* zcnt  = (unsigned*)alloc(256);    // zeroed by k_conv0 block 0
    double*   pS0   = (double*)alloc((size_t)64*256*8);
    double*   pQ0   = (double*)alloc((size_t)64*256*8);
    double*   A1B1  = (double*)alloc(256*8);
    double*   pS1   = (double*)alloc((size_t)128*1024*8);
    double*   pQ1   = (double*)alloc((size_t)128*1024*8);
    int8_t*   h0s   = (int8_t*)alloc((size_t)256*784*64);
    uint64_t* hp    = (uint64_t*)alloc((size_t)256*784*8);
    int16_t*  h1s   = (int16_t*)alloc((size_t)256*128*784*2);
    uint64_t* ap_t  = (uint64_t*)alloc((size_t)KW*256*8);
    uint64_t* wn1   = (uint64_t*)alloc(1152*8);
    uint64_t* wnz1  = (uint64_t*)alloc(1152*8);
    int16_t*  pcpart= (int16_t*)alloc((size_t)KS2*N1*BATCH*2);
    float*    af    = (float*)alloc((size_t)1024*256*4);
    float*    part9 = (float*)alloc((size_t)32*256*10*4);
    uint64_t* zlist = (uint64_t*)alloc((size_t)ZCAP*16);
    (void)ws_size; (void)in_sizes; (void)n_in; (void)out_size;

    k_conv0  <<<256,   256, 0, stream>>>(x, cw0, cp0, cw1, h0s, pS0, pQ0,
                                         wn1, wnz1, zcnt);
    k_pack_h0<<<784,   256, 0, stream>>>(h0s, pS0, pQ0, cg0, cb0, cp0, hp);
    k_conv1  <<<16384, 256, 0, stream>>>(hp, wn1, wnz1, cp1, h1s, pS1, pQ1);
    k_bnfin1 <<<128,   256, 0, stream>>>(pS1, pQ1, cg1, cb1, A1B1);
    k_pack_a0<<<25088, 256, 0, stream>>>(h1s, cp1, A1B1, ap_t);
    k_fc0g   <<<KS2*32,256, 0, stream>>>(fw0, ap_t, pcpart, zcnt, zlist);
    k_fc0ep  <<<1024,  256, 0, stream>>>(pcpart, zcnt, zlist, ap_t, fp0, fg0, fb0, af);
    k_fc1a   <<<32,    256, 0, stream>>>(af, fw1, part9);
    k_fc1b   <<<1,     256, 0, stream>>>(part9, fp1, fg1, fb1, scale, (float*)d_out);
}